// Round 2
// baseline (326.575 us; speedup 1.0000x reference)
//
#include <hip/hip_runtime.h>
#include <cstdint>

// Problem constants (from reference): m=8 batches, n=4096 points, dx=2,
// dz=16, grid 64x64 -> M=4096 grid points. ALL I/O IS FP32 (reference dtypes;
// R0's NaN in Output 0 proved the buffers are not bf16).
#define N_PTS   4096
#define M_GRID  4096
#define DZ      16
#define WAVES   8                 // waves per block, each owns an n-chunk
#define GPB     64                // grid points per block (one per lane)
#define NSUB    (N_PTS / WAVES)   // 512
#define REDSTR  17                // padded stride (floats) to kill LDS bank conflicts

// x_grid = broadcast of grid to (8, 64, 64, 2), fp32. 65536 floats total.
__global__ void xgrid_copy(const float* __restrict__ grid,
                           float* __restrict__ out) {
    int idx = blockIdx.x * blockDim.x + threadIdx.x;   // < 65536
    out[idx] = grid[idx & 8191];                       // grid has 8192 floats
}

// z_grid[b,g,:] = sum_n exp(-0.5*sum_d ((grid[g,d]-x[b,n,d])/ls[d])^2) * z[b,n,:]
// lane = grid point, wave = n-chunk; cross-wave combine via LDS.
__global__ __launch_bounds__(WAVES * 64)
void zgrid_kernel(const float2* __restrict__ x2,     // [8*4096] float2
                  const float4* __restrict__ z4,     // [8*4096*4] float4 (16 f/row)
                  const float*  __restrict__ lsp,    // [2]
                  const float2* __restrict__ grid2,  // [4096] float2
                  float*        __restrict__ out)    // z_grid region, fp32
{
    __shared__ float red[(WAVES - 1) * GPB * REDSTR];

    const int lane  = threadIdx.x & 63;
    const int w     = threadIdx.x >> 6;
    const int gtile = blockIdx.x;        // 0..63
    const int b     = blockIdx.y;        // 0..7
    const int g     = gtile * GPB + lane;

    // lengthscale = 1e-5 + softplus(param), per input dim (stable softplus)
    float p0 = lsp[0], p1 = lsp[1];
    float sp0 = (p0 > 0.f) ? (p0 + log1pf(expf(-p0))) : log1pf(expf(p0));
    float sp1 = (p1 > 0.f) ? (p1 + log1pf(expf(-p1))) : log1pf(expf(p1));
    float ls0 = 1e-5f + sp0, ls1 = 1e-5f + sp1;
    // fold -0.5 into per-dim quadratic coefficients: wgt = exp(q0*d0^2 + q1*d1^2)
    float q0 = -0.5f / (ls0 * ls0);
    float q1 = -0.5f / (ls1 * ls1);

    float2 gv = grid2[g];
    float g0 = gv.x, g1 = gv.y;

    float acc[DZ];
#pragma unroll
    for (int d = 0; d < DZ; ++d) acc[d] = 0.f;

    const float2* xb = x2 + b * N_PTS;
    const float4* zb = z4 + (size_t)b * N_PTS * 4;

    const int n0 = w * NSUB;
    for (int i = 0; i < NSUB; ++i) {
        int n = n0 + i;
        float2 xv = xb[n];                       // wave-uniform load (8 B)
        float d0 = g0 - xv.x;
        float d1 = g1 - xv.y;
        float e  = fmaf(d0 * q0, d0, d1 * q1 * d1);  // <= 0
        float wgt = __expf(e);
        const float4* zr = zb + (size_t)n * 4;   // wave-uniform loads (64 B)
        float4 za = zr[0], zc = zr[1], ze = zr[2], zg = zr[3];
        acc[0]  = fmaf(wgt, za.x, acc[0]);
        acc[1]  = fmaf(wgt, za.y, acc[1]);
        acc[2]  = fmaf(wgt, za.z, acc[2]);
        acc[3]  = fmaf(wgt, za.w, acc[3]);
        acc[4]  = fmaf(wgt, zc.x, acc[4]);
        acc[5]  = fmaf(wgt, zc.y, acc[5]);
        acc[6]  = fmaf(wgt, zc.z, acc[6]);
        acc[7]  = fmaf(wgt, zc.w, acc[7]);
        acc[8]  = fmaf(wgt, ze.x, acc[8]);
        acc[9]  = fmaf(wgt, ze.y, acc[9]);
        acc[10] = fmaf(wgt, ze.z, acc[10]);
        acc[11] = fmaf(wgt, ze.w, acc[11]);
        acc[12] = fmaf(wgt, zg.x, acc[12]);
        acc[13] = fmaf(wgt, zg.y, acc[13]);
        acc[14] = fmaf(wgt, zg.z, acc[14]);
        acc[15] = fmaf(wgt, zg.w, acc[15]);
    }

    // cross-wave reduction: waves 1..7 dump partials, wave 0 combines
    if (w > 0) {
        float* dst = red + ((w - 1) * GPB + lane) * REDSTR;
#pragma unroll
        for (int d = 0; d < DZ; ++d) dst[d] = acc[d];
    }
    __syncthreads();
    if (w == 0) {
#pragma unroll
        for (int j = 0; j < WAVES - 1; ++j) {
            const float* src = red + (j * GPB + lane) * REDSTR;
#pragma unroll
            for (int d = 0; d < DZ; ++d) acc[d] += src[d];
        }
        float4* op = reinterpret_cast<float4*>(out) + ((size_t)(b * M_GRID + g) * 4);
        op[0] = make_float4(acc[0],  acc[1],  acc[2],  acc[3]);
        op[1] = make_float4(acc[4],  acc[5],  acc[6],  acc[7]);
        op[2] = make_float4(acc[8],  acc[9],  acc[10], acc[11]);
        op[3] = make_float4(acc[12], acc[13], acc[14], acc[15]);
    }
}

extern "C" void kernel_launch(void* const* d_in, const int* in_sizes, int n_in,
                              void* d_out, int out_size, void* d_ws, size_t ws_size,
                              hipStream_t stream) {
    // inputs (setup_inputs order, all fp32): x [8,4096,2], z [8,4096,16],
    // lengthscale_param [2], grid [64,64,2]
    const float2* x2    = (const float2*)d_in[0];
    const float4* z4    = (const float4*)d_in[1];
    const float*  lsp   = (const float*)d_in[2];
    const float*  grid  = (const float*)d_in[3];
    float* out = (float*)d_out;

    // output: x_grid (65536 fp32) then z_grid (524288 fp32)
    hipLaunchKernelGGL(xgrid_copy, dim3(256), dim3(256), 0, stream,
                       grid, out);
    hipLaunchKernelGGL(zgrid_kernel, dim3(64, 8), dim3(WAVES * 64), 0, stream,
                       x2, z4, lsp, (const float2*)grid, out + 65536);
}

// Round 3
// 199.274 us; speedup vs baseline: 1.6388x; 1.6388x over previous
//
#include <hip/hip_runtime.h>
#include <cstdint>

// m=8, n=4096, dx=2, dz=16, grid 64x64 -> M=4096. All I/O fp32.
// Key structure: g = gtile*64 + lane -> grid dim0 coord is BLOCK-uniform,
// grid dim1 coord is per-lane. Each wave owns a wave-uniform n-chunk, so the
// dim0 distance test is identical across the wave -> coherent skip branch.
#define N_PTS   4096
#define M_GRID  4096
#define DZ      16
#define WAVES   8
#define GPB     64
#define NSUB    (N_PTS / WAVES)   // 512
#define REDSTR  17                // padded LDS stride (floats)
#define SKIP_E0 -20.0f            // exp(-20)=2e-9; total skip error < 4e-5

__global__ __launch_bounds__(WAVES * 64)
void setconv_kernel(const float2* __restrict__ x2,     // [8*4096]
                    const float4* __restrict__ z4,     // [8*4096*4]
                    const float*  __restrict__ lsp,    // [2]
                    const float2* __restrict__ grid2,  // [4096]
                    float2*       __restrict__ outx,   // x_grid [8*4096] float2
                    float*        __restrict__ outz)   // z_grid [8*4096*16]
{
    __shared__ float red[(WAVES - 1) * GPB * REDSTR];

    const int lane  = threadIdx.x & 63;
    const int w     = threadIdx.x >> 6;
    const int gtile = blockIdx.x;        // 0..63  (grid row)
    const int b     = blockIdx.y;        // 0..7
    const int g     = gtile * GPB + lane;

    // lengthscale = 1e-5 + softplus(param)  (stable softplus)
    float p0 = lsp[0], p1 = lsp[1];
    float sp0 = (p0 > 0.f) ? (p0 + log1pf(expf(-p0))) : log1pf(expf(p0));
    float sp1 = (p1 > 0.f) ? (p1 + log1pf(expf(-p1))) : log1pf(expf(p1));
    float ls0 = 1e-5f + sp0, ls1 = 1e-5f + sp1;
    float q0 = -0.5f / (ls0 * ls0);      // wgt = exp(q0*d0^2 + q1*d1^2)
    float q1 = -0.5f / (ls1 * ls1);

    float2 gv = grid2[g];
    const float g0 = gv.x;               // block-uniform (row coord)
    const float g1 = gv.y;               // per-lane (col coord)

    // fused x_grid write: x_grid[b,g,:] = grid[g,:]
    if (w == 0) outx[(size_t)b * M_GRID + g] = gv;

    float acc[DZ];
#pragma unroll
    for (int d = 0; d < DZ; ++d) acc[d] = 0.f;

    const float2* xw = x2 + b * N_PTS + w * NSUB;   // this wave's x chunk
    const float4* zb = z4 + (size_t)b * N_PTS * 4;
    const int nbase = w * NSUB;

    auto process = [&](const float2 (&xv)[8], int base) {
#pragma unroll
        for (int j = 0; j < 8; ++j) {
            float d0 = g0 - xv[j].x;
            float e0 = q0 * d0 * d0;     // identical across the wave
            if (e0 >= SKIP_E0) {         // coherent branch: s_cbranch_execz
                float d1  = g1 - xv[j].y;
                float wgt = __expf(fmaf(q1 * d1, d1, e0));
                const float4* zr = zb + (size_t)(base + j) * 4;
                float4 za = zr[0], zc = zr[1], ze = zr[2], zg = zr[3];
                acc[0]  = fmaf(wgt, za.x, acc[0]);
                acc[1]  = fmaf(wgt, za.y, acc[1]);
                acc[2]  = fmaf(wgt, za.z, acc[2]);
                acc[3]  = fmaf(wgt, za.w, acc[3]);
                acc[4]  = fmaf(wgt, zc.x, acc[4]);
                acc[5]  = fmaf(wgt, zc.y, acc[5]);
                acc[6]  = fmaf(wgt, zc.z, acc[6]);
                acc[7]  = fmaf(wgt, zc.w, acc[7]);
                acc[8]  = fmaf(wgt, ze.x, acc[8]);
                acc[9]  = fmaf(wgt, ze.y, acc[9]);
                acc[10] = fmaf(wgt, ze.z, acc[10]);
                acc[11] = fmaf(wgt, ze.w, acc[11]);
                acc[12] = fmaf(wgt, zg.x, acc[12]);
                acc[13] = fmaf(wgt, zg.y, acc[13]);
                acc[14] = fmaf(wgt, zg.z, acc[14]);
                acc[15] = fmaf(wgt, zg.w, acc[15]);
            }
        }
    };

    // double-buffered x prefetch, 8 points (64 B) per buffer
    float2 xa[8], xc[8];
#pragma unroll
    for (int j = 0; j < 8; ++j) xa[j] = xw[j];
    for (int i = 0; i < NSUB; i += 16) {
#pragma unroll
        for (int j = 0; j < 8; ++j) xc[j] = xw[i + 8 + j];
        process(xa, nbase + i);
        if (i + 16 < NSUB) {
#pragma unroll
            for (int j = 0; j < 8; ++j) xa[j] = xw[i + 16 + j];
        }
        process(xc, nbase + i + 8);
    }

    // cross-wave reduction: waves 1..7 dump partials, wave 0 combines
    if (w > 0) {
        float* dst = red + ((w - 1) * GPB + lane) * REDSTR;
#pragma unroll
        for (int d = 0; d < DZ; ++d) dst[d] = acc[d];
    }
    __syncthreads();
    if (w == 0) {
#pragma unroll
        for (int j = 0; j < WAVES - 1; ++j) {
            const float* src = red + (j * GPB + lane) * REDSTR;
#pragma unroll
            for (int d = 0; d < DZ; ++d) acc[d] += src[d];
        }
        float4* op = reinterpret_cast<float4*>(outz) + ((size_t)(b * M_GRID + g) * 4);
        op[0] = make_float4(acc[0],  acc[1],  acc[2],  acc[3]);
        op[1] = make_float4(acc[4],  acc[5],  acc[6],  acc[7]);
        op[2] = make_float4(acc[8],  acc[9],  acc[10], acc[11]);
        op[3] = make_float4(acc[12], acc[13], acc[14], acc[15]);
    }
}

extern "C" void kernel_launch(void* const* d_in, const int* in_sizes, int n_in,
                              void* d_out, int out_size, void* d_ws, size_t ws_size,
                              hipStream_t stream) {
    // inputs (all fp32): x [8,4096,2], z [8,4096,16], lengthscale_param [2],
    // grid [64,64,2]. output: x_grid (65536 f32) then z_grid (524288 f32).
    const float2* x2    = (const float2*)d_in[0];
    const float4* z4    = (const float4*)d_in[1];
    const float*  lsp   = (const float*)d_in[2];
    const float2* grid2 = (const float2*)d_in[3];
    float* out = (float*)d_out;

    hipLaunchKernelGGL(setconv_kernel, dim3(64, 8), dim3(WAVES * 64), 0, stream,
                       x2, z4, lsp, grid2, (float2*)out, out + 65536);
}